// Round 1
// baseline (1324.255 us; speedup 1.0000x reference)
//
#include <hip/hip_runtime.h>

// TSoftmaxLayer: out[bt,j] = sum_i softmax_i(w[bt,i,j]) * x[bt,i]
// B*T=16384, I=J=128, fp32. Memory-bound: one pass over 1 GiB of weights.
//
// Mapping: block = 8 (b,t) rows x 32 j-groups (256 threads). Each thread owns
// 4 consecutive j columns (float4 loads, 16B/lane coalescing) and runs an
// online softmax (running max m, denom l, weighted acc a) over i. x rows are
// staged in LDS and read as wave-broadcast.

#define I_DIM 128
#define J_DIM 128
#define ROWS 8
#define THREADS 256

__global__ __launch_bounds__(THREADS, 4)
void tsoftmax_mix_kernel(const float* __restrict__ x,   // [BT, I]
                         const float* __restrict__ w,   // [BT, I, J]
                         float* __restrict__ out,       // [BT, J]
                         int BT)
{
    __shared__ float xs[ROWS * I_DIM];

    const int tid = threadIdx.x;
    const long long bt0 = (long long)blockIdx.x * ROWS;

    // Stage this block's 8 x-rows (contiguous ROWS*I floats) into LDS.
    for (int k = tid; k < ROWS * I_DIM; k += THREADS) {
        long long g = bt0 * I_DIM + k;
        xs[k] = (bt0 + k / I_DIM < BT) ? x[g] : 0.0f;
    }
    __syncthreads();

    const int r  = tid >> 5;   // row within block [0,8)
    const int jg = tid & 31;   // j-group: columns [4*jg, 4*jg+4)
    const long long bt = bt0 + r;
    if (bt >= BT) return;

    const float* wrow = w + bt * (long long)(I_DIM * J_DIM) + jg * 4;
    const float* xrow = xs + r * I_DIM;

    // Online softmax state per owned column. -1e30f as "-inf": exp(-1e30-x)=0.
    float m0 = -1e30f, m1 = -1e30f, m2 = -1e30f, m3 = -1e30f;
    float l0 = 0.f, l1 = 0.f, l2 = 0.f, l3 = 0.f;
    float a0 = 0.f, a1 = 0.f, a2 = 0.f, a3 = 0.f;

#pragma unroll 4
    for (int i = 0; i < I_DIM; ++i) {
        const float4 wv = *reinterpret_cast<const float4*>(wrow + (long long)i * J_DIM);
        const float xi = xrow[i];

        {
            float mn = fmaxf(m0, wv.x);
            float c  = __expf(m0 - mn);
            float p  = __expf(wv.x - mn);
            l0 = l0 * c + p;
            a0 = a0 * c + p * xi;
            m0 = mn;
        }
        {
            float mn = fmaxf(m1, wv.y);
            float c  = __expf(m1 - mn);
            float p  = __expf(wv.y - mn);
            l1 = l1 * c + p;
            a1 = a1 * c + p * xi;
            m1 = mn;
        }
        {
            float mn = fmaxf(m2, wv.z);
            float c  = __expf(m2 - mn);
            float p  = __expf(wv.z - mn);
            l2 = l2 * c + p;
            a2 = a2 * c + p * xi;
            m2 = mn;
        }
        {
            float mn = fmaxf(m3, wv.w);
            float c  = __expf(m3 - mn);
            float p  = __expf(wv.w - mn);
            l3 = l3 * c + p;
            a3 = a3 * c + p * xi;
            m3 = mn;
        }
    }

    float4 o;
    o.x = a0 / l0;
    o.y = a1 / l1;
    o.z = a2 / l2;
    o.w = a3 / l3;
    *reinterpret_cast<float4*>(out + bt * J_DIM + jg * 4) = o;
}

extern "C" void kernel_launch(void* const* d_in, const int* in_sizes, int n_in,
                              void* d_out, int out_size, void* d_ws, size_t ws_size,
                              hipStream_t stream)
{
    const float* x = (const float*)d_in[0];   // inputs  [B,T,I]
    const float* w = (const float*)d_in[1];   // weights [B,T,I,J]
    float* out = (float*)d_out;               // [B,T,J]

    const int BT = in_sizes[0] / I_DIM;       // 16384
    const int blocks = (BT + ROWS - 1) / ROWS;

    hipLaunchKernelGGL(tsoftmax_mix_kernel, dim3(blocks), dim3(THREADS), 0, stream,
                       x, w, out, BT);
}